// Round 3
// baseline (12843.813 us; speedup 1.0000x reference)
//
#include <hip/hip_runtime.h>

// ---------------------------------------------------------------------------
// GRU scan on MI355X. Phase 1: bf16 GEMM P = X W^T + b. Phase 2: persistent
// scan, 2 groups x 32 wgs, U weights in VGPRs.
// R3: flag==data. Every cross-wg bf16 is a tagged u32 word (bf16<<16 | gen16)
// stored with one atomic dword at the coherence point (sc0 sc1). Consumers
// poll payload words directly -> 2 IF round trips per phase instead of 4.
// No barriers, no flags, no vmcnt-drain/release chains between wgs.
// Safety: producer writes gen t+1 only after consuming all gen-t data, which
// transitively implies every consumer finished reading gen t -> polls never
// skip a generation. 0xAA poison (tag 0xAAAA) never matches gen <= 1024.
// ---------------------------------------------------------------------------

typedef __attribute__((ext_vector_type(8))) __bf16 bf16x8;
typedef __attribute__((ext_vector_type(4))) float f32x4;
typedef __attribute__((ext_vector_type(4))) unsigned u32x4;
typedef unsigned short ushort_t;

#define DIM_ 1024
#define BATCH_ 32
#define T_ 1024
#define NC_ 3072  // 3*DIM

// workspace layout (bytes)
static constexpr size_t OFF_P     = 0;                    // bf16 32768x3072
static constexpr size_t OFF_XBF   = 201326592;            // bf16 32768x1024
static constexpr size_t OFF_WBF   = OFF_XBF + 67108864;   // bf16 3072x1024
static constexpr size_t OFF_UZR   = OFF_WBF + 6291456;    // bf16 2048x1024
static constexpr size_t OFF_UH    = OFF_UZR + 4194304;    // bf16 1024x1024
static constexpr size_t OFF_HBT   = OFF_UH  + 2097152;    // u32 2x16x1024 tagged h
static constexpr size_t OFF_RHT   = OFF_HBT + 131072;     // u32 2x16x1024 tagged r*h

__device__ __forceinline__ float b2f(ushort_t u) {
  union { float f; unsigned i; } v;
  v.i = ((unsigned)u) << 16;
  return v.f;
}
__device__ __forceinline__ ushort_t f2b(float f) {  // round-to-nearest-even
  union { float f; unsigned i; } v;
  v.f = f;
  unsigned r = v.i + 0x7fffu + ((v.i >> 16) & 1u);
  return (ushort_t)(r >> 16);
}

// --- coherence-point (IF) accessors ----------------------------------------
__device__ __forceinline__ void st_u32_sc(void* p, unsigned v) {
  asm volatile("global_store_dword %0, %1, off sc0 sc1" ::"v"(p), "v"(v)
               : "memory");
}
__device__ __forceinline__ u32x4 ld_u128_sc(const void* p) {
  u32x4 r;
  asm volatile("global_load_dwordx4 %0, %1, off sc0 sc1"
               : "=v"(r) : "v"(p) : "memory");
  return r;
}
__device__ __forceinline__ void vm_drain() {
  asm volatile("s_waitcnt vmcnt(0)" ::: "memory");
}
__device__ __forceinline__ bool tags_ok(u32x4 a, unsigned g) {
  unsigned m = (a.x ^ g) | (a.y ^ g) | (a.z ^ g) | (a.w ^ g);
  return (m & 0xFFFFu) == 0u;
}

// ------------------------------- converts ----------------------------------
__global__ void cvt_f32_bf16x4(const float4* __restrict__ src,
                               uint2* __restrict__ dst, int n4) {
  int i = blockIdx.x * blockDim.x + threadIdx.x;
  int st = gridDim.x * blockDim.x;
  for (; i < n4; i += st) {
    float4 v = src[i];
    unsigned a = (unsigned)f2b(v.x) | ((unsigned)f2b(v.y) << 16);
    unsigned b = (unsigned)f2b(v.z) | ((unsigned)f2b(v.w) << 16);
    dst[i] = make_uint2(a, b);
  }
}

// ------------------------------- GEMM --------------------------------------
__global__ __launch_bounds__(256) void gemm_xw(
    const ushort_t* __restrict__ A, const ushort_t* __restrict__ Bm,
    const float* __restrict__ bzr, const float* __restrict__ bh,
    ushort_t* __restrict__ C) {
  __shared__ ushort_t As[128][40];
  __shared__ ushort_t Bs[128][40];
  const int bi = blockIdx.x;
  const int p = bi / 192;
  const int q = bi % 192;
  const int i0 = (p * 8 + (q & 7)) * 128;
  const int n0 = (q >> 3) * 128;
  const int tid = threadIdx.x;
  const int w = tid >> 6, l = tid & 63;
  const int wr = w >> 1, wc = w & 1;
  const int quad = l >> 4, lr = l & 15;

  f32x4 acc[4][4] = {};
  for (int kc = 0; kc < 1024; kc += 32) {
    __syncthreads();
#pragma unroll
    for (int j = 0; j < 2; ++j) {
      int c = j * 256 + tid;
      int r = c >> 2, pp = c & 3;
      *(int4*)(&As[r][pp * 8]) =
          *(const int4*)(A + (size_t)(i0 + r) * 1024 + kc + pp * 8);
      *(int4*)(&Bs[r][pp * 8]) =
          *(const int4*)(Bm + (size_t)(n0 + r) * 1024 + kc + pp * 8);
    }
    __syncthreads();
    bf16x8 af[4], bfr[4];
#pragma unroll
    for (int mb = 0; mb < 4; ++mb)
      af[mb] = *(const bf16x8*)(&As[wr * 64 + mb * 16 + lr][quad * 8]);
#pragma unroll
    for (int nb = 0; nb < 4; ++nb)
      bfr[nb] = *(const bf16x8*)(&Bs[wc * 64 + nb * 16 + lr][quad * 8]);
#pragma unroll
    for (int mb = 0; mb < 4; ++mb)
#pragma unroll
      for (int nb = 0; nb < 4; ++nb)
        acc[mb][nb] = __builtin_amdgcn_mfma_f32_16x16x32_bf16(
            af[mb], bfr[nb], acc[mb][nb], 0, 0, 0);
  }
#pragma unroll
  for (int nb = 0; nb < 4; ++nb) {
    int col = n0 + wc * 64 + nb * 16 + lr;
    float bias = (col < 2048) ? bzr[col] : bh[col - 2048];
#pragma unroll
    for (int mb = 0; mb < 4; ++mb) {
#pragma unroll
      for (int reg = 0; reg < 4; ++reg) {
        int row = i0 + wr * 64 + mb * 16 + quad * 4 + reg;
        C[(size_t)row * NC_ + col] = f2b(acc[mb][nb][reg] + bias);
      }
    }
  }
}

// ------------------------------- scan --------------------------------------
__global__ __launch_bounds__(256, 1) void gru_scan(
    const ushort_t* __restrict__ P, const ushort_t* __restrict__ Uzr,
    const ushort_t* __restrict__ Uh, const float* __restrict__ h0,
    unsigned* __restrict__ HbT, unsigned* __restrict__ RHT,
    float* __restrict__ out) {
  const int g = blockIdx.x;
  const int G = g >> 5, gg = g & 31;
  const int rb0 = G * 16;   // batch base
  const int cs = gg * 32;   // column slice base
  const int tid = threadIdx.x;
  const int w = tid >> 6, l = tid & 63;
  const int quad = l >> 4, lr = l & 15;
  unsigned* HbT_g = HbT + G * 16384;  // [16][1024] tagged words
  unsigned* RHT_g = RHT + G * 16384;

  __shared__ ushort_t StageL[16][1032];  // staged bf16 payload
  __shared__ float Hl[16][33];           // fp32 master h slice
  __shared__ f32x4 red[2][64];           // phase-B k-split partials

  const int ctA = w >> 1, cbA = w & 1;
  const int khB = w >> 1, cbB = w & 1;
  const int eA = cs + cbA * 16 + lr;  // local col 0..1023 (phase A)
  const int eB = cs + cbB * 16 + lr;  // local col 0..1023 (phase B)
  const int c0 = tid * 4;             // staging columns [c0, c0+4)

  // ---- preload weights into VGPRs ----
  bf16x8 wa[32];
  {
    const ushort_t* urow = Uzr + (size_t)(ctA * 1024 + eA) * DIM_;
#pragma unroll
    for (int it = 0; it < 32; ++it)
      wa[it] = *(const bf16x8*)(urow + it * 32 + quad * 8);
  }
  bf16x8 wb[16];
  {
    const ushort_t* urow = Uh + (size_t)eB * DIM_ + khB * 512;
#pragma unroll
    for (int it = 0; it < 16; ++it)
      wb[it] = *(const bf16x8*)(urow + it * 32 + quad * 8);
  }

  // ---- init h slice: fp32 LDS master + tagged words (gen 0) ----
  {
    int s0 = tid * 2;
    int rr = s0 >> 5, cc = s0 & 31;
    float v0 = h0[(rb0 + rr) * DIM_ + cs + cc];
    float v1 = h0[(rb0 + rr) * DIM_ + cs + cc + 1];
    Hl[rr][cc] = v0;
    Hl[rr][cc + 1] = v1;
    st_u32_sc(&HbT_g[rr * 1024 + cs + cc], ((unsigned)f2b(v0) << 16));
    st_u32_sc(&HbT_g[rr * 1024 + cs + cc + 1], ((unsigned)f2b(v1) << 16));
  }

  // prefetch P for t=0 (plain cached loads)
  float pA[4], pB[4];
  {
    const size_t prow = (size_t)rb0 * NC_;
#pragma unroll
    for (int reg = 0; reg < 4; ++reg) {
      int br = quad * 4 + reg;
      pA[reg] = b2f(P[prow + (size_t)br * NC_ + ctA * 1024 + eA]);
      pB[reg] = b2f(P[prow + (size_t)br * NC_ + 2048 + eB]);
    }
  }

  for (int t = 0; t < T_; ++t) {
    const unsigned tagH = (unsigned)(t & 0xFFFF);       // h input to step t
    const unsigned tagR = (unsigned)(t & 0xFFFF);       // r*h of step t
    const unsigned tagH1 = (unsigned)((t + 1) & 0xFFFF);

    // ---------------- stage tagged h (poll) into LDS ----------------
    __syncthreads();  // StageL free of previous readers
    {
      const unsigned* src = HbT_g + c0;
      u32x4 tmp[16];
#pragma unroll
      for (int j = 0; j < 16; ++j) tmp[j] = ld_u128_sc(src + j * 1024);
      vm_drain();
#pragma unroll
      for (int j = 0; j < 16; ++j) {
        u32x4 v = tmp[j];
        while (!tags_ok(v, tagH)) {
          v = ld_u128_sc(src + j * 1024);
          vm_drain();
        }
        tmp[j] = v;
      }
#pragma unroll
      for (int j = 0; j < 16; ++j) {
        unsigned lo = (tmp[j].x >> 16) | (tmp[j].y & 0xFFFF0000u);
        unsigned hi = (tmp[j].z >> 16) | (tmp[j].w & 0xFFFF0000u);
        *(uint2*)&StageL[j][c0] = make_uint2(lo, hi);
      }
    }
    __syncthreads();

    // ---------------- phase A: z and r ----------------
    f32x4 acc0 = {0.f, 0.f, 0.f, 0.f}, acc1 = {0.f, 0.f, 0.f, 0.f};
#pragma unroll
    for (int it = 0; it < 32; it += 2) {
      bf16x8 a0 = *(const bf16x8*)&StageL[lr][it * 32 + quad * 8];
      bf16x8 a1 = *(const bf16x8*)&StageL[lr][(it + 1) * 32 + quad * 8];
      acc0 = __builtin_amdgcn_mfma_f32_16x16x32_bf16(a0, wa[it], acc0, 0, 0, 0);
      acc1 =
          __builtin_amdgcn_mfma_f32_16x16x32_bf16(a1, wa[it + 1], acc1, 0, 0, 0);
    }
    f32x4 acc = acc0 + acc1;
    float zv[4];
#pragma unroll
    for (int reg = 0; reg < 4; ++reg) {
      int br = quad * 4 + reg;
      float pre = acc[reg] + pA[reg];
      float sv = 1.f / (1.f + __expf(-pre));
      if (ctA == 0) {
        zv[reg] = sv;  // z stays in registers (same lane map in phase B)
      } else {
        float hv = Hl[br][cbA * 16 + lr];
        st_u32_sc(&RHT_g[br * 1024 + eA],
                  ((unsigned)f2b(sv * hv) << 16) | tagR);
      }
    }

    // ---------------- stage tagged r*h (poll) into LDS ----------------
    __syncthreads();  // phase-A StageL readers done
    {
      const unsigned* src = RHT_g + c0;
      u32x4 tmp[16];
#pragma unroll
      for (int j = 0; j < 16; ++j) tmp[j] = ld_u128_sc(src + j * 1024);
      vm_drain();
#pragma unroll
      for (int j = 0; j < 16; ++j) {
        u32x4 v = tmp[j];
        while (!tags_ok(v, tagR)) {
          v = ld_u128_sc(src + j * 1024);
          vm_drain();
        }
        tmp[j] = v;
      }
#pragma unroll
      for (int j = 0; j < 16; ++j) {
        unsigned lo = (tmp[j].x >> 16) | (tmp[j].y & 0xFFFF0000u);
        unsigned hi = (tmp[j].z >> 16) | (tmp[j].w & 0xFFFF0000u);
        *(uint2*)&StageL[j][c0] = make_uint2(lo, hi);
      }
    }
    __syncthreads();

    // ---------------- phase B: h~ and update ----------------
    f32x4 b0 = {0.f, 0.f, 0.f, 0.f}, b1 = {0.f, 0.f, 0.f, 0.f};
#pragma unroll
    for (int it = 0; it < 16; it += 2) {
      bf16x8 a0 = *(const bf16x8*)&StageL[lr][khB * 512 + it * 32 + quad * 8];
      bf16x8 a1 =
          *(const bf16x8*)&StageL[lr][khB * 512 + (it + 1) * 32 + quad * 8];
      b0 = __builtin_amdgcn_mfma_f32_16x16x32_bf16(a0, wb[it], b0, 0, 0, 0);
      b1 = __builtin_amdgcn_mfma_f32_16x16x32_bf16(a1, wb[it + 1], b1, 0, 0, 0);
    }
    f32x4 acch = b0 + b1;
    if (w >= 2) red[cbB][l] = acch;
    __syncthreads();
    if (w < 2) {
      f32x4 oth4 = red[cbB][l];
#pragma unroll
      for (int reg = 0; reg < 4; ++reg) {
        int br = quad * 4 + reg;
        float ax = pB[reg] + acch[reg] + oth4[reg];
        float e = __expf(2.f * fabsf(ax));
        float th = copysignf(1.f - 2.f / (e + 1.f), ax);
        float hv = Hl[br][cbB * 16 + lr];
        float z = zv[reg];
        float hn = (1.f - z) * hv + z * th;
        Hl[br][cbB * 16 + lr] = hn;
        st_u32_sc(&HbT_g[br * 1024 + eB], ((unsigned)f2b(hn) << 16) | tagH1);
        out[((size_t)t * BATCH_ + rb0 + br) * DIM_ + eB] = hn;
      }
    }

    // prefetch P for t+1 (plain cached; absorbed by next poll's waitcnt)
    {
      int tn = (t + 1 < T_) ? t + 1 : t;
      const size_t prow = ((size_t)(tn * BATCH_ + rb0)) * NC_;
#pragma unroll
      for (int reg = 0; reg < 4; ++reg) {
        int br = quad * 4 + reg;
        pA[reg] = b2f(P[prow + (size_t)br * NC_ + ctA * 1024 + eA]);
        pB[reg] = b2f(P[prow + (size_t)br * NC_ + 2048 + eB]);
      }
    }
  }
}

// ------------------------------- launch ------------------------------------
extern "C" void kernel_launch(void* const* d_in, const int* in_sizes, int n_in,
                              void* d_out, int out_size, void* d_ws,
                              size_t ws_size, hipStream_t stream) {
  const float* x   = (const float*)d_in[0];
  const float* h0  = (const float*)d_in[1];
  const float* Wzr = (const float*)d_in[2];
  const float* Uzr = (const float*)d_in[3];
  const float* Wh  = (const float*)d_in[4];
  const float* Uh  = (const float*)d_in[5];
  const float* bzr = (const float*)d_in[6];
  const float* bh  = (const float*)d_in[7];
  char* ws = (char*)d_ws;
  ushort_t* P     = (ushort_t*)(ws + OFF_P);
  ushort_t* Xbf   = (ushort_t*)(ws + OFF_XBF);
  ushort_t* Wbf   = (ushort_t*)(ws + OFF_WBF);
  ushort_t* Uzrb  = (ushort_t*)(ws + OFF_UZR);
  ushort_t* Uhb   = (ushort_t*)(ws + OFF_UH);
  unsigned* HbT   = (unsigned*)(ws + OFF_HBT);
  unsigned* RHT   = (unsigned*)(ws + OFF_RHT);
  float* out = (float*)d_out;

  cvt_f32_bf16x4<<<1024, 256, 0, stream>>>((const float4*)x, (uint2*)Xbf,
                                           33554432 / 4);
  cvt_f32_bf16x4<<<256, 256, 0, stream>>>((const float4*)Wzr, (uint2*)Wbf,
                                          2097152 / 4);
  cvt_f32_bf16x4<<<128, 256, 0, stream>>>((const float4*)Wh,
                                          (uint2*)(Wbf + 2097152), 1048576 / 4);
  cvt_f32_bf16x4<<<256, 256, 0, stream>>>((const float4*)Uzr, (uint2*)Uzrb,
                                          2097152 / 4);
  cvt_f32_bf16x4<<<128, 256, 0, stream>>>((const float4*)Uh, (uint2*)Uhb,
                                          1048576 / 4);
  gemm_xw<<<6144, 256, 0, stream>>>(Xbf, Wbf, bzr, bh, P);
  gru_scan<<<64, 256, 0, stream>>>(P, Uzrb, Uhb, h0, HbT, RHT, out);
}